// Round 7
// baseline (36.136 us; speedup 1.0000x reference)
//
#include <hip/hip_runtime.h>

// ---------------------------------------------------------------------------
// Hopfield block, B=131072 independent problems of S=14, D=16 -> softmax(7).
// One batch spread over all 64 lanes. EVERY reduction is an MFMA:
//   mean  = mfma(0.0625s, x16)            (reduce d, broadcast)
//   Ex2   = mfma(0.0625s, x16*x16)        (reduce d, broadcast)
//   T     = mfma(MT, xh, C=r)             (t_s[dd] + r[dd])
//   P     = mfma(xh, W2T)                 (P[s][c], s in regs)
//   SS    = mfma(xh, T+r)                 (scores^T: SS[k][s] + rho[k])
//   Z     = mfma(ones, E)                 (softmax denom, broadcast)
//   G     = mfma(f*E, P)                  (G[s][c])
//   z     = mfma(ones, G, C=const2)       (reduce s, broadcast)
// Zero cross-lane ops in the batch loop (no shuffles, no LDS); only the
// shared 7-way softmax epilogue uses 4 DPP row-rotate adds.
// ---------------------------------------------------------------------------

#define NBATCH 131072

typedef float    f32x4 __attribute__((ext_vector_type(4)));
typedef _Float16 f16x4 __attribute__((ext_vector_type(4)));
typedef __fp16   h16x2 __attribute__((ext_vector_type(2)));

#define ROR(x,N) __int_as_float(__builtin_amdgcn_update_dpp(0, __float_as_int(x), 0x120 + (N), 0xF, 0xF, false))

static __device__ __forceinline__ f16x4 cvt4(float a, float b, float c, float d) {
    union { f16x4 v; h16x2 h[2]; } u;
    u.h[0] = __builtin_amdgcn_cvt_pkrtz(a, b);
    u.h[1] = __builtin_amdgcn_cvt_pkrtz(c, d);
    return u.v;
}

static __device__ __forceinline__ f32x4 mfma16(f16x4 a, f16x4 b, f32x4 c) {
#if __has_builtin(__builtin_amdgcn_mfma_f32_16x16x16f16)
    return __builtin_amdgcn_mfma_f32_16x16x16f16(a, b, c, 0, 0, 0);
#else
    f32x4 d;
    asm("v_mfma_f32_16x16x16_f16 %0, %1, %2, %3" : "=v"(d) : "v"(a), "v"(b), "v"(c));
    return d;
#endif
}

// ---------------------------------------------------------------------------
// Pre-kernel: fold weights into ws (all f32):
//   ws[  0..255]  MT[dd][d]  = M[d][dd],  M = Wq'^T Wk'  (Wx' = g_x (.) Wx)
//   ws[256..271]  r[dd]      = sum_e bq'[e] Wk'[e,dd]    (bq' = bq + Wq@b_lnq)
//   ws[272..527]  W2pad[c][d] 16x16, rows c=7..15 zero;  W2 = (Wb@Wo)@Wv'
//   ws[528..543]  const2[c] (c<7), zero-padded
//   ws[544..559]  wm[s] (s<14), zero-padded
// ---------------------------------------------------------------------------
__global__ __launch_bounds__(256) void hop_prep(
    const float* __restrict__ gq, const float* __restrict__ bq_ln,
    const float* __restrict__ gk,
    const float* __restrict__ gv, const float* __restrict__ bv_ln,
    const float* __restrict__ Wq, const float* __restrict__ bq,
    const float* __restrict__ Wk,
    const float* __restrict__ Wv, const float* __restrict__ bv,
    const float* __restrict__ Wo, const float* __restrict__ bo,
    const float* __restrict__ Wm, const float* __restrict__ bm,
    const float* __restrict__ Wb, const float* __restrict__ bb,
    float* __restrict__ ws)
{
    __shared__ float WqP[256], WkP[256], WvP[256];
    __shared__ float bqP[16], bvP[16], WcS[112];
    const int t = threadIdx.x;
    {
        const int d = t & 15;
        WqP[t] = Wq[t] * gq[d];
        WkP[t] = Wk[t] * gk[d];
        WvP[t] = Wv[t] * gv[d];
    }
    if (t < 16) {
        float a = bq[t], c = bv[t];
        for (int d = 0; d < 16; ++d) {
            a = fmaf(Wq[t*16+d], bq_ln[d], a);
            c = fmaf(Wv[t*16+d], bv_ln[d], c);
        }
        bqP[t] = a; bvP[t] = c;
    }
    if (t < 112) {   // Wc = Wb@Wo (7x16), depends only on globals
        const int c = t >> 4, e = t & 15;
        float s = 0.f;
        for (int o = 0; o < 128; ++o) s = fmaf(Wb[c*128+o], Wo[o*16+e], s);
        WcS[t] = s;
    }
    __syncthreads();
    {   // MT (transposed M): ws[dd*16+d] = M[d][dd]
        const int dd = t >> 4, d = t & 15;
        float m = 0.f;
        for (int e = 0; e < 16; ++e) m = fmaf(WqP[e*16+d], WkP[e*16+dd], m);
        ws[t] = m;
    }
    if (t < 16) {
        float rr = 0.f;
        for (int e = 0; e < 16; ++e) rr = fmaf(bqP[e], WkP[e*16+t], rr);
        ws[256 + t] = rr;
    }
    {   // W2pad: 16x16, rows c>=7 zero
        const int c = t >> 4, d = t & 15;
        float s = 0.f;
        if (c < 7)
            for (int e = 0; e < 16; ++e) s = fmaf(WcS[c*16+e], WvP[e*16+d], s);
        ws[272 + t] = s;
    }
    if (t < 16) {
        float v = 0.f;
        if (t < 7) {
            float wmsum = 0.f;
            for (int s = 0; s < 14; ++s) wmsum += Wm[s];
            float s1 = 0.f;
            for (int e = 0; e < 16; ++e) s1 = fmaf(WcS[t*16+e], bvP[e], s1);
            float s2 = 0.f, s3 = 0.f;
            for (int o = 0; o < 128; ++o) { s2 = fmaf(Wb[t*128+o], bo[o], s2); s3 += Wb[t*128+o]; }
            v = wmsum*s1 + wmsum*s2 + bm[0]*s3 + bb[t];
        }
        ws[528 + t] = v;
        ws[544 + t] = (t < 14) ? Wm[t] : 0.0f;
    }
}

// ---------------------------------------------------------------------------
// Main kernel: one wave = 4 batches, each batch spread across 64 lanes.
// Fragment convention (v_mfma_f32_16x16x16_f16), lane l: col=l&15, q=l>>4:
//   A[m=col][k=4q+i]   B[k=4q+i][n=col]   D[m=4q+i][n=col]
// A-frag and B-frag are the SAME per-lane layout; D feeds back as a B-frag
// with its m-dim becoming the next contraction dim.
// ---------------------------------------------------------------------------
__global__ __launch_bounds__(256) void hop_main(const float* __restrict__ smp,
                                                const float* __restrict__ W,
                                                float* __restrict__ out)
{
    const int wid = (blockIdx.x * 256 + threadIdx.x) >> 6;   // global wave id
    const int l   = threadIdx.x & 63;
    const int col = l & 15;    // free-dim index (s / k / c depending on op)
    const int q   = l >> 4;    // reg-chunk selector
    const size_t gbase = (size_t)wid * 4;

    // one-time constant fragments
    const float4 mt = *reinterpret_cast<const float4*>(W + col*16 + q*4);        // MT A-frag
    const float4 w2 = *reinterpret_cast<const float4*>(W + 272 + col*16 + q*4);  // W2T B-frag
    const float4 r4 = *reinterpret_cast<const float4*>(W + 256 + q*4);           // r chunk
    const float wm_l = W[544 + col];
    const float c2_l = W[528 + col];
    const f16x4 mtA  = cvt4(mt.x, mt.y, mt.z, mt.w);
    const f16x4 w2B  = cvt4(w2.x, w2.y, w2.z, w2.w);
    const f16x4 ONE  = {(_Float16)1.0f, (_Float16)1.0f, (_Float16)1.0f, (_Float16)1.0f};
    const f16x4 SIXT = {(_Float16)0.0625f, (_Float16)0.0625f, (_Float16)0.0625f, (_Float16)0.0625f};
    const f32x4 zero = {0.f, 0.f, 0.f, 0.f};
    const f32x4 rC   = {r4.x, r4.y, r4.z, r4.w};
    const f32x4 c2C  = {c2_l, c2_l, c2_l, c2_l};
    const float L2E  = 1.4426950408889634f;

    const int srow = (col < 14) ? col : 13;                  // clamp pad rows
    const float* bp = smp + gbase * 224 + srow * 16 + q * 4;

    float zb0, zb1, zb2, zb3;
    #pragma unroll
    for (int bb = 0; bb < 4; ++bb) {
        const float4 x = *reinterpret_cast<const float4*>(bp + bb * 224);

        // LN stats via reduce-MFMAs: mean & E[x^2] replicated per row
        const f16x4 xf  = cvt4(x.x, x.y, x.z, x.w);
        const f16x4 xqf = cvt4(x.x*x.x, x.y*x.y, x.z*x.z, x.w*x.w);
        const f32x4 S1 = mfma16(SIXT, xf,  zero);    // mean_s, all regs
        const f32x4 S2 = mfma16(SIXT, xqf, zero);    // E[x^2]_s, all regs
        const float mean = S1[0];
        const float var  = fmaf(-mean, mean, S2[0]);
        const float rstd = __builtin_amdgcn_rsqf(var + 1e-5f);
        const float nmr  = -mean * rstd;
        const f16x4 xhA = cvt4(fmaf(x.x, rstd, nmr), fmaf(x.y, rstd, nmr),
                               fmaf(x.z, rstd, nmr), fmaf(x.w, rstd, nmr));

        // P = xh @ W2^T  (P[s][c], s in regs)
        const f32x4 P = mfma16(xhA, w2B, zero);
        // T = MT @ xh^T + r  (r folded via C-operand)
        const f32x4 T = mfma16(mtA, xhA, rC);
        const f16x4 B2 = cvt4(T[0], T[1], T[2], T[3]);
        // SS = scores^T: lane holds SS[k=4q+i][s=col] (+rho[k])
        const f32x4 SS = mfma16(xhA, B2, zero);

        // exp (scores bounded -> no max subtraction); kill pad keys k=14,15
        const bool hi = (q == 3);
        const float e0 = __builtin_amdgcn_exp2f(SS[0] * L2E);
        const float e1 = __builtin_amdgcn_exp2f(SS[1] * L2E);
        float e2 = __builtin_amdgcn_exp2f(SS[2] * L2E);
        float e3 = __builtin_amdgcn_exp2f(SS[3] * L2E);
        e2 = hi ? 0.0f : e2;
        e3 = hi ? 0.0f : e3;

        // Z_s via reduce-MFMA (broadcast), then f = wm_s / Z_s
        const f16x4 Ef16 = cvt4(e0, e1, e2, e3);
        const f32x4 Zm = mfma16(ONE, Ef16, zero);
        const float f = wm_l * __builtin_amdgcn_rcpf(Zm[0]);

        // G = (f*E)^T @ P : G[s][c], s in regs
        const f16x4 EfA = cvt4(e0*f, e1*f, e2*f, e3*f);
        const f16x4 Pf  = cvt4(P[0], P[1], P[2], P[3]);
        const f32x4 G = mfma16(EfA, Pf, zero);

        // z[c] = sum_s G[s][c] + const2[c] via reduce-MFMA (C = const2)
        const f16x4 Gf = cvt4(G[0], G[1], G[2], G[3]);
        const f32x4 ZZ = mfma16(ONE, Gf, c2C);
        const float zz = ZZ[0];

        if      (bb == 0) zb0 = zz;
        else if (bb == 1) zb1 = zz;
        else if (bb == 2) zb2 = zz;
        else              zb3 = zz;
    }

    // shared softmax7: lane-group q handles batch gbase+q
    float z = (q == 1) ? zb1 : zb0;
    z = (q == 2) ? zb2 : z;
    z = (q == 3) ? zb3 : z;
    float e = (col < 7) ? __builtin_amdgcn_exp2f(z * L2E) : 0.0f;
    float s = e;
    s += ROR(s, 1); s += ROR(s, 2); s += ROR(s, 4); s += ROR(s, 8);
    if (col < 7) out[(gbase + q) * 7 + col] = e * __builtin_amdgcn_rcpf(s);
}

extern "C" void kernel_launch(void* const* d_in, const int* in_sizes, int n_in,
                              void* d_out, int out_size, void* d_ws, size_t ws_size,
                              hipStream_t stream) {
    (void)in_sizes; (void)n_in; (void)out_size; (void)ws_size;
    const float* smp = (const float*)d_in[0];
    float* ws = (float*)d_ws;
    hop_prep<<<1, 256, 0, stream>>>(
        (const float*)d_in[1],  (const float*)d_in[2],   // ln_q_g, ln_q_b
        (const float*)d_in[3],                           // ln_k_g
        (const float*)d_in[5],  (const float*)d_in[6],   // ln_v_g, ln_v_b
        (const float*)d_in[7],  (const float*)d_in[8],   // Wq, bq
        (const float*)d_in[9],                           // Wk
        (const float*)d_in[11], (const float*)d_in[12],  // Wv, bv
        (const float*)d_in[13], (const float*)d_in[14],  // Wo, bo
        (const float*)d_in[15], (const float*)d_in[16],  // Wm, bm
        (const float*)d_in[17], (const float*)d_in[18],  // Wb, bb
        ws);
    hop_main<<<NBATCH * 16 / 256, 256, 0, stream>>>(smp, ws, (float*)d_out);
}

// Round 8
// 34.433 us; speedup vs baseline: 1.0495x; 1.0495x over previous
//
#include <hip/hip_runtime.h>

// ---------------------------------------------------------------------------
// Hopfield block, B=131072 independent problems of S=14, D=16 -> softmax(7).
// One batch spread over all 64 lanes; every reduction is an MFMA.
// Persistent-wave version: 8192 waves, each handling 4 iterations x 4 batches
// with double-buffered prefetch so global loads stay in flight continuously.
//   stats: mean,Ex2 = mfma(1/16, x)         (reduce d, broadcast)
//   T  = mfma(MT*L2E, xh, C=r*L2E)          (score projection, log2-scaled)
//   SS = mfma(xh, T)                        (scores^T, log2 units)
//   P  = mfma(xh, W2T)                      (P[key][c], key in regs)
//   E  = exp2(SS)        Zt = mfma(E, ONES) (Z_s lands in the REG dim)
//   G' = mfma(E, P)                         (unnormalized output)
//   z  = mfma(wm*L2E/Z, G', C=const2*L2E)   (normalization folded in here)
// Chain depth 5 MFMAs; rcp runs parallel to G'. No cross-lane ops in the
// batch path; epilogue softmax7 uses 4 DPP row-rotate adds.
// ---------------------------------------------------------------------------

#define NBATCH 131072
#define NWAVES 8192                       // 2048 blocks x 4 waves = full residency
#define ITERF  ((size_t)NWAVES * 896)     // float stride between iterations

typedef float    f32x4 __attribute__((ext_vector_type(4)));
typedef _Float16 f16x4 __attribute__((ext_vector_type(4)));
typedef __fp16   h16x2 __attribute__((ext_vector_type(2)));

#define ROR(x,N) __int_as_float(__builtin_amdgcn_update_dpp(0, __float_as_int(x), 0x120 + (N), 0xF, 0xF, false))

static __device__ __forceinline__ f16x4 cvt4(float a, float b, float c, float d) {
    union { f16x4 v; h16x2 h[2]; } u;
    u.h[0] = __builtin_amdgcn_cvt_pkrtz(a, b);
    u.h[1] = __builtin_amdgcn_cvt_pkrtz(c, d);
    return u.v;
}

static __device__ __forceinline__ f32x4 mfma16(f16x4 a, f16x4 b, f32x4 c) {
#if __has_builtin(__builtin_amdgcn_mfma_f32_16x16x16f16)
    return __builtin_amdgcn_mfma_f32_16x16x16f16(a, b, c, 0, 0, 0);
#else
    f32x4 d;
    asm("v_mfma_f32_16x16x16_f16 %0, %1, %2, %3" : "=v"(d) : "v"(a), "v"(b), "v"(c));
    return d;
#endif
}

// ---------------------------------------------------------------------------
// Pre-kernel: fold weights into ws (all f32). L2E = log2(e) pre-baked into
// MT, r, wm, const2 so the main kernel uses exp2 directly with no scaling.
//   ws[  0..255]  MT[dd][d]*L2E   (M = Wq'^T Wk', Wx' = g_x (.) Wx)
//   ws[256..271]  r[dd]*L2E       (r = bq'^T Wk', bq' = bq + Wq@b_lnq)
//   ws[272..527]  W2pad[c][d] 16x16, rows c=7..15 zero;  W2 = (Wb@Wo)@Wv'
//   ws[528..543]  const2[c]*L2E (c<7), zero-padded
//   ws[544..559]  wm[s]*L2E (s<14), zero-padded
// ---------------------------------------------------------------------------
__global__ __launch_bounds__(256) void hop_prep(
    const float* __restrict__ gq, const float* __restrict__ bq_ln,
    const float* __restrict__ gk,
    const float* __restrict__ gv, const float* __restrict__ bv_ln,
    const float* __restrict__ Wq, const float* __restrict__ bq,
    const float* __restrict__ Wk,
    const float* __restrict__ Wv, const float* __restrict__ bv,
    const float* __restrict__ Wo, const float* __restrict__ bo,
    const float* __restrict__ Wm, const float* __restrict__ bm,
    const float* __restrict__ Wb, const float* __restrict__ bb,
    float* __restrict__ ws)
{
    const float L2E = 1.4426950408889634f;
    __shared__ float WqP[256], WkP[256], WvP[256];
    __shared__ float bqP[16], bvP[16], WcS[112];
    const int t = threadIdx.x;
    {
        const int d = t & 15;
        WqP[t] = Wq[t] * gq[d];
        WkP[t] = Wk[t] * gk[d];
        WvP[t] = Wv[t] * gv[d];
    }
    if (t < 16) {
        float a = bq[t], c = bv[t];
        for (int d = 0; d < 16; ++d) {
            a = fmaf(Wq[t*16+d], bq_ln[d], a);
            c = fmaf(Wv[t*16+d], bv_ln[d], c);
        }
        bqP[t] = a; bvP[t] = c;
    }
    if (t < 112) {   // Wc = Wb@Wo (7x16), depends only on globals
        const int c = t >> 4, e = t & 15;
        float s = 0.f;
        for (int o = 0; o < 128; ++o) s = fmaf(Wb[c*128+o], Wo[o*16+e], s);
        WcS[t] = s;
    }
    __syncthreads();
    {   // MT (transposed M), log2-scaled: ws[dd*16+d] = M[d][dd]*L2E
        const int dd = t >> 4, d = t & 15;
        float m = 0.f;
        for (int e = 0; e < 16; ++e) m = fmaf(WqP[e*16+d], WkP[e*16+dd], m);
        ws[t] = m * L2E;
    }
    if (t < 16) {
        float rr = 0.f;
        for (int e = 0; e < 16; ++e) rr = fmaf(bqP[e], WkP[e*16+t], rr);
        ws[256 + t] = rr * L2E;
    }
    {   // W2pad: 16x16, rows c>=7 zero
        const int c = t >> 4, d = t & 15;
        float s = 0.f;
        if (c < 7)
            for (int e = 0; e < 16; ++e) s = fmaf(WcS[c*16+e], WvP[e*16+d], s);
        ws[272 + t] = s;
    }
    if (t < 16) {
        float v = 0.f;
        if (t < 7) {
            float wmsum = 0.f;
            for (int s = 0; s < 14; ++s) wmsum += Wm[s];
            float s1 = 0.f;
            for (int e = 0; e < 16; ++e) s1 = fmaf(WcS[t*16+e], bvP[e], s1);
            float s2 = 0.f, s3 = 0.f;
            for (int o = 0; o < 128; ++o) { s2 = fmaf(Wb[t*128+o], bo[o], s2); s3 += Wb[t*128+o]; }
            v = wmsum*s1 + wmsum*s2 + bm[0]*s3 + bb[t];
        }
        ws[528 + t] = v * L2E;
        ws[544 + t] = (t < 14) ? Wm[t] * L2E : 0.0f;
    }
}

// ---------------------------------------------------------------------------
// Main kernel. Fragment convention (v_mfma_f32_16x16x16_f16), lane l:
//   col=l&15, q=l>>4;  A[m=col][k=4q+i]  B[k=4q+i][n=col]  D[m=4q+i][n=col]
// A- and B-frags share the same physical layout, so feeding a D result back
// as A gives the transposed contraction (used by Zt to move Z_s into regs).
// ---------------------------------------------------------------------------
__global__ __launch_bounds__(256, 4) void hop_main(const float* __restrict__ smp,
                                                   const float* __restrict__ W,
                                                   float* __restrict__ out)
{
    const int wave = (blockIdx.x * 256 + threadIdx.x) >> 6;   // 0..NWAVES-1
    const int l    = threadIdx.x & 63;
    const int col  = l & 15;
    const int q    = l >> 4;

    // one-time constant fragments
    const float4 mt  = *reinterpret_cast<const float4*>(W + col*16 + q*4);
    const float4 w2  = *reinterpret_cast<const float4*>(W + 272 + col*16 + q*4);
    const float4 r4  = *reinterpret_cast<const float4*>(W + 256 + q*4);
    const float4 wm4 = *reinterpret_cast<const float4*>(W + 544 + q*4);
    const float  c2_l = W[528 + col];
    const f16x4 mtA  = cvt4(mt.x, mt.y, mt.z, mt.w);
    const f16x4 w2B  = cvt4(w2.x, w2.y, w2.z, w2.w);
    const f16x4 ONE  = {(_Float16)1.0f, (_Float16)1.0f, (_Float16)1.0f, (_Float16)1.0f};
    const f16x4 SIXT = {(_Float16)0.0625f, (_Float16)0.0625f, (_Float16)0.0625f, (_Float16)0.0625f};
    const f32x4 zero = {0.f, 0.f, 0.f, 0.f};
    const f32x4 rC   = {r4.x, r4.y, r4.z, r4.w};
    const f32x4 c2C  = {c2_l, c2_l, c2_l, c2_l};
    const bool  hi   = (q == 3);

    const int srow = (col < 14) ? col : 13;                  // clamp pad rows
    const float* p0 = smp + (size_t)wave * 896 + srow * 16 + q * 4;
    float* op = out + ((size_t)wave * 4 + q) * 7 + col;
    const size_t OSTEP = (size_t)NWAVES * 4 * 7;

    auto zbatch = [&](const float4& x) -> float {
        // LN stats via reduce-MFMAs (replicated per row)
        const f16x4 xf  = cvt4(x.x, x.y, x.z, x.w);
        const f16x4 xqf = cvt4(x.x*x.x, x.y*x.y, x.z*x.z, x.w*x.w);
        const f32x4 S1 = mfma16(SIXT, xf,  zero);
        const f32x4 S2 = mfma16(SIXT, xqf, zero);
        const float mean = S1[0];
        const float var  = fmaf(-mean, mean, S2[0]);
        const float rstd = __builtin_amdgcn_rsqf(var + 1e-5f);
        const float nmr  = -mean * rstd;
        const f16x4 xhA = cvt4(fmaf(x.x, rstd, nmr), fmaf(x.y, rstd, nmr),
                               fmaf(x.z, rstd, nmr), fmaf(x.w, rstd, nmr));
        // P[key][c] (key in regs) -- independent branch
        const f32x4 P = mfma16(xhA, w2B, zero);
        // T = MT@xh^T + r (log2-scaled), then scores^T (log2 units)
        const f32x4 T  = mfma16(mtA, xhA, rC);
        const f16x4 B2 = cvt4(T[0], T[1], T[2], T[3]);
        const f32x4 SS = mfma16(xhA, B2, zero);
        // exp2 (scores bounded, no max subtraction); kill pad keys 14,15
        const float e0 = __builtin_amdgcn_exp2f(SS[0]);
        const float e1 = __builtin_amdgcn_exp2f(SS[1]);
        const float e2 = hi ? 0.0f : __builtin_amdgcn_exp2f(SS[2]);
        const float e3 = hi ? 0.0f : __builtin_amdgcn_exp2f(SS[3]);
        const f16x4 E  = cvt4(e0, e1, e2, e3);
        const f16x4 Pf = cvt4(P[0], P[1], P[2], P[3]);
        // Zt: E fed as A transposes the reduce -> Z_s lands in the REG dim
        const f32x4 Zt = mfma16(E, ONE, zero);
        const f32x4 G  = mfma16(E, Pf,  zero);    // unnormalized output
        const float w0 = wm4.x * __builtin_amdgcn_rcpf(Zt[0]);
        const float w1 = wm4.y * __builtin_amdgcn_rcpf(Zt[1]);
        const float w2s = wm4.z * __builtin_amdgcn_rcpf(Zt[2]);
        const float w3 = wm4.w * __builtin_amdgcn_rcpf(Zt[3]);
        const f16x4 wA = cvt4(w0, w1, w2s, w3);
        const f16x4 Gf = cvt4(G[0], G[1], G[2], G[3]);
        // z_c = sum_s (wm_s/Z_s) G'[s][c] + const2_c  (log2-scaled)
        const f32x4 ZZ = mfma16(wA, Gf, c2C);
        return ZZ[0];
    };

    auto epilogue = [&](float z0, float z1, float z2, float z3, float* o) {
        float z = (q == 1) ? z1 : z0;
        z = (q == 2) ? z2 : z;
        z = (q == 3) ? z3 : z;
        float e = (col < 7) ? __builtin_amdgcn_exp2f(z) : 0.0f;
        float s = e;
        s += ROR(s, 1); s += ROR(s, 2); s += ROR(s, 4); s += ROR(s, 8);
        if (col < 7) *o = e * __builtin_amdgcn_rcpf(s);
    };

#define LD4(v0, v1, v2, v3, it) { const float* pp = p0 + (size_t)(it) * ITERF; \
    v0 = *reinterpret_cast<const float4*>(pp);        \
    v1 = *reinterpret_cast<const float4*>(pp + 224);  \
    v2 = *reinterpret_cast<const float4*>(pp + 448);  \
    v3 = *reinterpret_cast<const float4*>(pp + 672); }

    float4 a0, a1, a2, a3, b0, b1, b2, b3;
    LD4(a0, a1, a2, a3, 0);
    LD4(b0, b1, b2, b3, 1);
    epilogue(zbatch(a0), zbatch(a1), zbatch(a2), zbatch(a3), op);
    LD4(a0, a1, a2, a3, 2);
    epilogue(zbatch(b0), zbatch(b1), zbatch(b2), zbatch(b3), op + OSTEP);
    LD4(b0, b1, b2, b3, 3);
    epilogue(zbatch(a0), zbatch(a1), zbatch(a2), zbatch(a3), op + 2*OSTEP);
    epilogue(zbatch(b0), zbatch(b1), zbatch(b2), zbatch(b3), op + 3*OSTEP);
#undef LD4
}

extern "C" void kernel_launch(void* const* d_in, const int* in_sizes, int n_in,
                              void* d_out, int out_size, void* d_ws, size_t ws_size,
                              hipStream_t stream) {
    (void)in_sizes; (void)n_in; (void)out_size; (void)ws_size;
    const float* smp = (const float*)d_in[0];
    float* ws = (float*)d_ws;
    hop_prep<<<1, 256, 0, stream>>>(
        (const float*)d_in[1],  (const float*)d_in[2],   // ln_q_g, ln_q_b
        (const float*)d_in[3],                           // ln_k_g
        (const float*)d_in[5],  (const float*)d_in[6],   // ln_v_g, ln_v_b
        (const float*)d_in[7],  (const float*)d_in[8],   // Wq, bq
        (const float*)d_in[9],                           // Wk
        (const float*)d_in[11], (const float*)d_in[12],  // Wv, bv
        (const float*)d_in[13], (const float*)d_in[14],  // Wo, bo
        (const float*)d_in[15], (const float*)d_in[16],  // Wm, bm
        (const float*)d_in[17], (const float*)d_in[18],  // Wb, bb
        ws);
    hop_main<<<NWAVES * 64 / 256, 256, 0, stream>>>(smp, ws, (float*)d_out);
}

// Round 9
// 31.733 us; speedup vs baseline: 1.1388x; 1.0851x over previous
//
#include <hip/hip_runtime.h>

// ---------------------------------------------------------------------------
// Hopfield block, B=131072 independent problems of S=14, D=16 -> softmax(7).
// One batch spread over all 64 lanes; every reduction is an MFMA.
// Persistent-wave version: 8192 waves, each handling 4 iterations x 4 batches
// with double-buffered prefetch. THIS ROUND: sample loads are NONTEMPORAL
// (streaming, no cache allocation) to unlock the read path; out stores nt too.
//   stats: mean,Ex2 = mfma(1/16, x)         (reduce d, broadcast)
//   T  = mfma(MT*L2E, xh, C=r*L2E)          (score projection, log2-scaled)
//   SS = mfma(xh, T)                        (scores^T, log2 units)
//   P  = mfma(xh, W2T)                      (P[key][c], key in regs)
//   E  = exp2(SS)        Zt = mfma(E, ONES) (Z_s lands in the REG dim)
//   G' = mfma(E, P)                         (unnormalized output)
//   z  = mfma(wm*L2E/Z, G', C=const2*L2E)   (normalization folded in here)
// ---------------------------------------------------------------------------

#define NBATCH 131072
#define NWAVES 8192                       // 2048 blocks x 4 waves = full residency
#define ITERF  ((size_t)NWAVES * 896)     // float stride between iterations

typedef float    f32x4 __attribute__((ext_vector_type(4)));
typedef _Float16 f16x4 __attribute__((ext_vector_type(4)));
typedef __fp16   h16x2 __attribute__((ext_vector_type(2)));

#define ROR(x,N) __int_as_float(__builtin_amdgcn_update_dpp(0, __float_as_int(x), 0x120 + (N), 0xF, 0xF, false))

static __device__ __forceinline__ f16x4 cvt4(float a, float b, float c, float d) {
    union { f16x4 v; h16x2 h[2]; } u;
    u.h[0] = __builtin_amdgcn_cvt_pkrtz(a, b);
    u.h[1] = __builtin_amdgcn_cvt_pkrtz(c, d);
    return u.v;
}

static __device__ __forceinline__ f32x4 mfma16(f16x4 a, f16x4 b, f32x4 c) {
#if __has_builtin(__builtin_amdgcn_mfma_f32_16x16x16f16)
    return __builtin_amdgcn_mfma_f32_16x16x16f16(a, b, c, 0, 0, 0);
#else
    f32x4 d;
    asm("v_mfma_f32_16x16x16_f16 %0, %1, %2, %3" : "=v"(d) : "v"(a), "v"(b), "v"(c));
    return d;
#endif
}

// ---------------------------------------------------------------------------
// Pre-kernel: fold weights into ws (all f32). L2E = log2(e) pre-baked into
// MT, r, wm, const2 so the main kernel uses exp2 directly with no scaling.
//   ws[  0..255]  MT[dd][d]*L2E   (M = Wq'^T Wk', Wx' = g_x (.) Wx)
//   ws[256..271]  r[dd]*L2E       (r = bq'^T Wk', bq' = bq + Wq@b_lnq)
//   ws[272..527]  W2pad[c][d] 16x16, rows c=7..15 zero;  W2 = (Wb@Wo)@Wv'
//   ws[528..543]  const2[c]*L2E (c<7), zero-padded
//   ws[544..559]  wm[s]*L2E (s<14), zero-padded
// ---------------------------------------------------------------------------
__global__ __launch_bounds__(256) void hop_prep(
    const float* __restrict__ gq, const float* __restrict__ bq_ln,
    const float* __restrict__ gk,
    const float* __restrict__ gv, const float* __restrict__ bv_ln,
    const float* __restrict__ Wq, const float* __restrict__ bq,
    const float* __restrict__ Wk,
    const float* __restrict__ Wv, const float* __restrict__ bv,
    const float* __restrict__ Wo, const float* __restrict__ bo,
    const float* __restrict__ Wm, const float* __restrict__ bm,
    const float* __restrict__ Wb, const float* __restrict__ bb,
    float* __restrict__ ws)
{
    const float L2E = 1.4426950408889634f;
    __shared__ float WqP[256], WkP[256], WvP[256];
    __shared__ float bqP[16], bvP[16], WcS[112];
    const int t = threadIdx.x;
    {
        const int d = t & 15;
        WqP[t] = Wq[t] * gq[d];
        WkP[t] = Wk[t] * gk[d];
        WvP[t] = Wv[t] * gv[d];
    }
    if (t < 16) {
        float a = bq[t], c = bv[t];
        for (int d = 0; d < 16; ++d) {
            a = fmaf(Wq[t*16+d], bq_ln[d], a);
            c = fmaf(Wv[t*16+d], bv_ln[d], c);
        }
        bqP[t] = a; bvP[t] = c;
    }
    if (t < 112) {   // Wc = Wb@Wo (7x16), depends only on globals
        const int c = t >> 4, e = t & 15;
        float s = 0.f;
        for (int o = 0; o < 128; ++o) s = fmaf(Wb[c*128+o], Wo[o*16+e], s);
        WcS[t] = s;
    }
    __syncthreads();
    {   // MT (transposed M), log2-scaled: ws[dd*16+d] = M[d][dd]*L2E
        const int dd = t >> 4, d = t & 15;
        float m = 0.f;
        for (int e = 0; e < 16; ++e) m = fmaf(WqP[e*16+d], WkP[e*16+dd], m);
        ws[t] = m * L2E;
    }
    if (t < 16) {
        float rr = 0.f;
        for (int e = 0; e < 16; ++e) rr = fmaf(bqP[e], WkP[e*16+t], rr);
        ws[256 + t] = rr * L2E;
    }
    {   // W2pad: 16x16, rows c>=7 zero
        const int c = t >> 4, d = t & 15;
        float s = 0.f;
        if (c < 7)
            for (int e = 0; e < 16; ++e) s = fmaf(WcS[c*16+e], WvP[e*16+d], s);
        ws[272 + t] = s;
    }
    if (t < 16) {
        float v = 0.f;
        if (t < 7) {
            float wmsum = 0.f;
            for (int s = 0; s < 14; ++s) wmsum += Wm[s];
            float s1 = 0.f;
            for (int e = 0; e < 16; ++e) s1 = fmaf(WcS[t*16+e], bvP[e], s1);
            float s2 = 0.f, s3 = 0.f;
            for (int o = 0; o < 128; ++o) { s2 = fmaf(Wb[t*128+o], bo[o], s2); s3 += Wb[t*128+o]; }
            v = wmsum*s1 + wmsum*s2 + bm[0]*s3 + bb[t];
        }
        ws[528 + t] = v * L2E;
        ws[544 + t] = (t < 14) ? Wm[t] * L2E : 0.0f;
    }
}

// ---------------------------------------------------------------------------
// Main kernel. Fragment convention (v_mfma_f32_16x16x16_f16), lane l:
//   col=l&15, q=l>>4;  A[m=col][k=4q+i]  B[k=4q+i][n=col]  D[m=4q+i][n=col]
// ---------------------------------------------------------------------------
__global__ __launch_bounds__(256, 4) void hop_main(const float* __restrict__ smp,
                                                   const float* __restrict__ W,
                                                   float* __restrict__ out)
{
    const int wave = (blockIdx.x * 256 + threadIdx.x) >> 6;   // 0..NWAVES-1
    const int l    = threadIdx.x & 63;
    const int col  = l & 15;
    const int q    = l >> 4;

    // one-time constant fragments (cached loads: reused by every block)
    const float4 mt  = *reinterpret_cast<const float4*>(W + col*16 + q*4);
    const float4 w2  = *reinterpret_cast<const float4*>(W + 272 + col*16 + q*4);
    const float4 r4  = *reinterpret_cast<const float4*>(W + 256 + q*4);
    const float4 wm4 = *reinterpret_cast<const float4*>(W + 544 + q*4);
    const float  c2_l = W[528 + col];
    const f16x4 mtA  = cvt4(mt.x, mt.y, mt.z, mt.w);
    const f16x4 w2B  = cvt4(w2.x, w2.y, w2.z, w2.w);
    const f16x4 ONE  = {(_Float16)1.0f, (_Float16)1.0f, (_Float16)1.0f, (_Float16)1.0f};
    const f16x4 SIXT = {(_Float16)0.0625f, (_Float16)0.0625f, (_Float16)0.0625f, (_Float16)0.0625f};
    const f32x4 zero = {0.f, 0.f, 0.f, 0.f};
    const f32x4 rC   = {r4.x, r4.y, r4.z, r4.w};
    const f32x4 c2C  = {c2_l, c2_l, c2_l, c2_l};
    const bool  hi   = (q == 3);

    const int srow = (col < 14) ? col : 13;                  // clamp pad rows
    const float* p0 = smp + (size_t)wave * 896 + srow * 16 + q * 4;
    float* op = out + ((size_t)wave * 4 + q) * 7 + col;
    const size_t OSTEP = (size_t)NWAVES * 4 * 7;

    auto zbatch = [&](const f32x4& x) -> float {
        // LN stats via reduce-MFMAs (replicated per row)
        const f16x4 xf  = cvt4(x[0], x[1], x[2], x[3]);
        const f16x4 xqf = cvt4(x[0]*x[0], x[1]*x[1], x[2]*x[2], x[3]*x[3]);
        const f32x4 S1 = mfma16(SIXT, xf,  zero);
        const f32x4 S2 = mfma16(SIXT, xqf, zero);
        const float mean = S1[0];
        const float var  = fmaf(-mean, mean, S2[0]);
        const float rstd = __builtin_amdgcn_rsqf(var + 1e-5f);
        const float nmr  = -mean * rstd;
        const f16x4 xhA = cvt4(fmaf(x[0], rstd, nmr), fmaf(x[1], rstd, nmr),
                               fmaf(x[2], rstd, nmr), fmaf(x[3], rstd, nmr));
        // P[key][c] (key in regs) -- independent branch
        const f32x4 P = mfma16(xhA, w2B, zero);
        // T = MT@xh^T + r (log2-scaled), then scores^T (log2 units)
        const f32x4 T  = mfma16(mtA, xhA, rC);
        const f16x4 B2 = cvt4(T[0], T[1], T[2], T[3]);
        const f32x4 SS = mfma16(xhA, B2, zero);
        // exp2 (scores bounded, no max subtraction); kill pad keys 14,15
        const float e0 = __builtin_amdgcn_exp2f(SS[0]);
        const float e1 = __builtin_amdgcn_exp2f(SS[1]);
        const float e2 = hi ? 0.0f : __builtin_amdgcn_exp2f(SS[2]);
        const float e3 = hi ? 0.0f : __builtin_amdgcn_exp2f(SS[3]);
        const f16x4 E  = cvt4(e0, e1, e2, e3);
        const f16x4 Pf = cvt4(P[0], P[1], P[2], P[3]);
        // Zt: E fed as A transposes the reduce -> Z_s lands in the REG dim
        const f32x4 Zt = mfma16(E, ONE, zero);
        const f32x4 G  = mfma16(E, Pf,  zero);    // unnormalized output
        const float w0 = wm4.x * __builtin_amdgcn_rcpf(Zt[0]);
        const float w1 = wm4.y * __builtin_amdgcn_rcpf(Zt[1]);
        const float w2s = wm4.z * __builtin_amdgcn_rcpf(Zt[2]);
        const float w3 = wm4.w * __builtin_amdgcn_rcpf(Zt[3]);
        const f16x4 wA = cvt4(w0, w1, w2s, w3);
        const f16x4 Gf = cvt4(G[0], G[1], G[2], G[3]);
        // z_c = sum_s (wm_s/Z_s) G'[s][c] + const2_c  (log2-scaled)
        const f32x4 ZZ = mfma16(wA, Gf, c2C);
        return ZZ[0];
    };

    auto epilogue = [&](float z0, float z1, float z2, float z3, float* o) {
        float z = (q == 1) ? z1 : z0;
        z = (q == 2) ? z2 : z;
        z = (q == 3) ? z3 : z;
        float e = (col < 7) ? __builtin_amdgcn_exp2f(z) : 0.0f;
        float s = e;
        s += ROR(s, 1); s += ROR(s, 2); s += ROR(s, 4); s += ROR(s, 8);
        if (col < 7) __builtin_nontemporal_store(e * __builtin_amdgcn_rcpf(s), o);
    };

    // nontemporal streaming loads: use-once data, don't allocate in L2/L3
#define LD4(v0, v1, v2, v3, it) { const float* pp = p0 + (size_t)(it) * ITERF; \
    v0 = __builtin_nontemporal_load(reinterpret_cast<const f32x4*>(pp));        \
    v1 = __builtin_nontemporal_load(reinterpret_cast<const f32x4*>(pp + 224));  \
    v2 = __builtin_nontemporal_load(reinterpret_cast<const f32x4*>(pp + 448));  \
    v3 = __builtin_nontemporal_load(reinterpret_cast<const f32x4*>(pp + 672)); }

    f32x4 a0, a1, a2, a3, b0, b1, b2, b3;
    LD4(a0, a1, a2, a3, 0);
    LD4(b0, b1, b2, b3, 1);
    epilogue(zbatch(a0), zbatch(a1), zbatch(a2), zbatch(a3), op);
    LD4(a0, a1, a2, a3, 2);
    epilogue(zbatch(b0), zbatch(b1), zbatch(b2), zbatch(b3), op + OSTEP);
    LD4(b0, b1, b2, b3, 3);
    epilogue(zbatch(a0), zbatch(a1), zbatch(a2), zbatch(a3), op + 2*OSTEP);
    epilogue(zbatch(b0), zbatch(b1), zbatch(b2), zbatch(b3), op + 3*OSTEP);
#undef LD4
}

extern "C" void kernel_launch(void* const* d_in, const int* in_sizes, int n_in,
                              void* d_out, int out_size, void* d_ws, size_t ws_size,
                              hipStream_t stream) {
    (void)in_sizes; (void)n_in; (void)out_size; (void)ws_size;
    const float* smp = (const float*)d_in[0];
    float* ws = (float*)d_ws;
    hop_prep<<<1, 256, 0, stream>>>(
        (const float*)d_in[1],  (const float*)d_in[2],   // ln_q_g, ln_q_b
        (const float*)d_in[3],                           // ln_k_g
        (const float*)d_in[5],  (const float*)d_in[6],   // ln_v_g, ln_v_b
        (const float*)d_in[7],  (const float*)d_in[8],   // Wq, bq
        (const float*)d_in[9],                           // Wk
        (const float*)d_in[11], (const float*)d_in[12],  // Wv, bv
        (const float*)d_in[13], (const float*)d_in[14],  // Wo, bo
        (const float*)d_in[15], (const float*)d_in[16],  // Wm, bm
        (const float*)d_in[17], (const float*)d_in[18],  // Wb, bb
        ws);
    hop_main<<<NWAVES * 64 / 256, 256, 0, stream>>>(smp, ws, (float*)d_out);
}

// Round 10
// 31.580 us; speedup vs baseline: 1.1443x; 1.0049x over previous
//
#include <hip/hip_runtime.h>

// ---------------------------------------------------------------------------
// Hopfield block, B=131072 independent problems of S=14, D=16 -> softmax(7).
// One batch spread over all 64 lanes; every reduction is an MFMA.
// THIS ROUND: occupancy-first. Non-persistent grid (8192 blocks x 4 waves,
// one wave = 4 batches), all 4 sample loads hoisted (NT), and
// __launch_bounds__(256,8) to force <=64 VGPR -> 8 waves/SIMD residency.
// sched_barrier(0) between batch chains keeps register pressure low.
//   stats: mean,Ex2 = mfma(1/16, x)         (reduce d, broadcast)
//   T  = mfma(MT*L2E, xh, C=r*L2E)          (score projection, log2-scaled)
//   SS = mfma(xh, T)                        (scores^T, log2 units)
//   P  = mfma(xh, W2T)                      (P[key][c], key in regs)
//   E  = exp2(SS)        Zt = mfma(E, ONES) (Z_s lands in the REG dim)
//   G' = mfma(E, P)                         (unnormalized output)
//   z  = mfma(wm*L2E/Z, G', C=const2*L2E)   (normalization folded in here)
// ---------------------------------------------------------------------------

#define NBATCH 131072

typedef float    f32x4 __attribute__((ext_vector_type(4)));
typedef _Float16 f16x4 __attribute__((ext_vector_type(4)));
typedef __fp16   h16x2 __attribute__((ext_vector_type(2)));

#define ROR(x,N) __int_as_float(__builtin_amdgcn_update_dpp(0, __float_as_int(x), 0x120 + (N), 0xF, 0xF, false))

static __device__ __forceinline__ f16x4 cvt4(float a, float b, float c, float d) {
    union { f16x4 v; h16x2 h[2]; } u;
    u.h[0] = __builtin_amdgcn_cvt_pkrtz(a, b);
    u.h[1] = __builtin_amdgcn_cvt_pkrtz(c, d);
    return u.v;
}

static __device__ __forceinline__ f32x4 mfma16(f16x4 a, f16x4 b, f32x4 c) {
#if __has_builtin(__builtin_amdgcn_mfma_f32_16x16x16f16)
    return __builtin_amdgcn_mfma_f32_16x16x16f16(a, b, c, 0, 0, 0);
#else
    f32x4 d;
    asm("v_mfma_f32_16x16x16_f16 %0, %1, %2, %3" : "=v"(d) : "v"(a), "v"(b), "v"(c));
    return d;
#endif
}

// ---------------------------------------------------------------------------
// Pre-kernel: fold weights into ws (all f32). L2E = log2(e) pre-baked into
// MT, r, wm, const2 so the main kernel uses exp2 directly with no scaling.
//   ws[  0..255]  MT[dd][d]*L2E   (M = Wq'^T Wk', Wx' = g_x (.) Wx)
//   ws[256..271]  r[dd]*L2E       (r = bq'^T Wk', bq' = bq + Wq@b_lnq)
//   ws[272..527]  W2pad[c][d] 16x16, rows c=7..15 zero;  W2 = (Wb@Wo)@Wv'
//   ws[528..543]  const2[c]*L2E (c<7), zero-padded
//   ws[544..559]  wm[s]*L2E (s<14), zero-padded
// ---------------------------------------------------------------------------
__global__ __launch_bounds__(256) void hop_prep(
    const float* __restrict__ gq, const float* __restrict__ bq_ln,
    const float* __restrict__ gk,
    const float* __restrict__ gv, const float* __restrict__ bv_ln,
    const float* __restrict__ Wq, const float* __restrict__ bq,
    const float* __restrict__ Wk,
    const float* __restrict__ Wv, const float* __restrict__ bv,
    const float* __restrict__ Wo, const float* __restrict__ bo,
    const float* __restrict__ Wm, const float* __restrict__ bm,
    const float* __restrict__ Wb, const float* __restrict__ bb,
    float* __restrict__ ws)
{
    const float L2E = 1.4426950408889634f;
    __shared__ float WqP[256], WkP[256], WvP[256];
    __shared__ float bqP[16], bvP[16], WcS[112];
    const int t = threadIdx.x;
    {
        const int d = t & 15;
        WqP[t] = Wq[t] * gq[d];
        WkP[t] = Wk[t] * gk[d];
        WvP[t] = Wv[t] * gv[d];
    }
    if (t < 16) {
        float a = bq[t], c = bv[t];
        for (int d = 0; d < 16; ++d) {
            a = fmaf(Wq[t*16+d], bq_ln[d], a);
            c = fmaf(Wv[t*16+d], bv_ln[d], c);
        }
        bqP[t] = a; bvP[t] = c;
    }
    if (t < 112) {   // Wc = Wb@Wo (7x16), depends only on globals
        const int c = t >> 4, e = t & 15;
        float s = 0.f;
        for (int o = 0; o < 128; ++o) s = fmaf(Wb[c*128+o], Wo[o*16+e], s);
        WcS[t] = s;
    }
    __syncthreads();
    {   // MT (transposed M), log2-scaled: ws[dd*16+d] = M[d][dd]*L2E
        const int dd = t >> 4, d = t & 15;
        float m = 0.f;
        for (int e = 0; e < 16; ++e) m = fmaf(WqP[e*16+d], WkP[e*16+dd], m);
        ws[t] = m * L2E;
    }
    if (t < 16) {
        float rr = 0.f;
        for (int e = 0; e < 16; ++e) rr = fmaf(bqP[e], WkP[e*16+t], rr);
        ws[256 + t] = rr * L2E;
    }
    {   // W2pad: 16x16, rows c>=7 zero
        const int c = t >> 4, d = t & 15;
        float s = 0.f;
        if (c < 7)
            for (int e = 0; e < 16; ++e) s = fmaf(WcS[c*16+e], WvP[e*16+d], s);
        ws[272 + t] = s;
    }
    if (t < 16) {
        float v = 0.f;
        if (t < 7) {
            float wmsum = 0.f;
            for (int s = 0; s < 14; ++s) wmsum += Wm[s];
            float s1 = 0.f;
            for (int e = 0; e < 16; ++e) s1 = fmaf(WcS[t*16+e], bvP[e], s1);
            float s2 = 0.f, s3 = 0.f;
            for (int o = 0; o < 128; ++o) { s2 = fmaf(Wb[t*128+o], bo[o], s2); s3 += Wb[t*128+o]; }
            v = wmsum*s1 + wmsum*s2 + bm[0]*s3 + bb[t];
        }
        ws[528 + t] = v * L2E;
        ws[544 + t] = (t < 14) ? Wm[t] * L2E : 0.0f;
    }
}

// ---------------------------------------------------------------------------
// Main kernel. Fragment convention (v_mfma_f32_16x16x16_f16), lane l:
//   col=l&15, q=l>>4;  A[m=col][k=4q+i]  B[k=4q+i][n=col]  D[m=4q+i][n=col]
// __launch_bounds__(256,8): force <=64 VGPR so 8 waves/SIMD are resident
// (32 waves/CU) -- the memory-level-parallelism lever.
// ---------------------------------------------------------------------------
__global__ __launch_bounds__(256, 8) void hop_main(const float* __restrict__ smp,
                                                   const float* __restrict__ W,
                                                   float* __restrict__ out)
{
    const int wave = (blockIdx.x * 256 + threadIdx.x) >> 6;   // 0..32767
    const int l    = threadIdx.x & 63;
    const int col  = l & 15;
    const int q    = l >> 4;

    // one-time constant fragments (cached loads: reused by every block)
    const float4 mt  = *reinterpret_cast<const float4*>(W + col*16 + q*4);
    const float4 w2  = *reinterpret_cast<const float4*>(W + 272 + col*16 + q*4);
    const float4 r4  = *reinterpret_cast<const float4*>(W + 256 + q*4);
    const float4 wm4 = *reinterpret_cast<const float4*>(W + 544 + q*4);
    const float  c2_l = W[528 + col];
    const f16x4 mtA  = cvt4(mt.x, mt.y, mt.z, mt.w);
    const f16x4 w2B  = cvt4(w2.x, w2.y, w2.z, w2.w);
    const f16x4 ONE  = {(_Float16)1.0f, (_Float16)1.0f, (_Float16)1.0f, (_Float16)1.0f};
    const f16x4 SIXT = {(_Float16)0.0625f, (_Float16)0.0625f, (_Float16)0.0625f, (_Float16)0.0625f};
    const f32x4 zero = {0.f, 0.f, 0.f, 0.f};
    const f32x4 rC   = {r4.x, r4.y, r4.z, r4.w};
    const f32x4 c2C  = {c2_l, c2_l, c2_l, c2_l};
    const bool  hi   = (q == 3);

    const int srow = (col < 14) ? col : 13;                  // clamp pad rows
    const float* p0 = smp + (size_t)wave * 896 + srow * 16 + q * 4;
    float* op = out + ((size_t)wave * 4 + q) * 7 + col;

    auto zbatch = [&](const f32x4& x) -> float {
        // LN stats via reduce-MFMAs (replicated per row)
        const f16x4 xf  = cvt4(x[0], x[1], x[2], x[3]);
        const f16x4 xqf = cvt4(x[0]*x[0], x[1]*x[1], x[2]*x[2], x[3]*x[3]);
        const f32x4 S1 = mfma16(SIXT, xf,  zero);
        const f32x4 S2 = mfma16(SIXT, xqf, zero);
        const float mean = S1[0];
        const float var  = fmaf(-mean, mean, S2[0]);
        const float rstd = __builtin_amdgcn_rsqf(var + 1e-5f);
        const float nmr  = -mean * rstd;
        const f16x4 xhA = cvt4(fmaf(x[0], rstd, nmr), fmaf(x[1], rstd, nmr),
                               fmaf(x[2], rstd, nmr), fmaf(x[3], rstd, nmr));
        // P[key][c] (key in regs) -- independent branch
        const f32x4 P = mfma16(xhA, w2B, zero);
        // T = MT@xh^T + r (log2-scaled), then scores^T (log2 units)
        const f32x4 T  = mfma16(mtA, xhA, rC);
        const f16x4 B2 = cvt4(T[0], T[1], T[2], T[3]);
        const f32x4 SS = mfma16(xhA, B2, zero);
        // exp2 (scores bounded, no max subtraction); kill pad keys 14,15
        const float e0 = __builtin_amdgcn_exp2f(SS[0]);
        const float e1 = __builtin_amdgcn_exp2f(SS[1]);
        const float e2 = hi ? 0.0f : __builtin_amdgcn_exp2f(SS[2]);
        const float e3 = hi ? 0.0f : __builtin_amdgcn_exp2f(SS[3]);
        const f16x4 E  = cvt4(e0, e1, e2, e3);
        const f16x4 Pf = cvt4(P[0], P[1], P[2], P[3]);
        // Zt: E fed as A transposes the reduce -> Z_s lands in the REG dim
        const f32x4 Zt = mfma16(E, ONE, zero);
        const f32x4 G  = mfma16(E, Pf,  zero);    // unnormalized output
        const float w0 = wm4.x * __builtin_amdgcn_rcpf(Zt[0]);
        const float w1 = wm4.y * __builtin_amdgcn_rcpf(Zt[1]);
        const float w2s = wm4.z * __builtin_amdgcn_rcpf(Zt[2]);
        const float w3 = wm4.w * __builtin_amdgcn_rcpf(Zt[3]);
        const f16x4 wA = cvt4(w0, w1, w2s, w3);
        const f16x4 Gf = cvt4(G[0], G[1], G[2], G[3]);
        // z_c = sum_s (wm_s/Z_s) G'[s][c] + const2_c  (log2-scaled)
        const f32x4 ZZ = mfma16(wA, Gf, c2C);
        return ZZ[0];
    };

    // hoist all 4 batch loads (NT, 4 KB in flight per wave before compute)
    const f32x4 a0 = __builtin_nontemporal_load(reinterpret_cast<const f32x4*>(p0));
    const f32x4 a1 = __builtin_nontemporal_load(reinterpret_cast<const f32x4*>(p0 + 224));
    const f32x4 a2 = __builtin_nontemporal_load(reinterpret_cast<const f32x4*>(p0 + 448));
    const f32x4 a3 = __builtin_nontemporal_load(reinterpret_cast<const f32x4*>(p0 + 672));

    // sched_barrier(0) between chains: prevent cross-batch interleaving from
    // quadrupling the live set (keep VGPR <= 64; TLP hides the serial latency)
    const float z0 = zbatch(a0);
    __builtin_amdgcn_sched_barrier(0);
    const float z1 = zbatch(a1);
    __builtin_amdgcn_sched_barrier(0);
    const float z2 = zbatch(a2);
    __builtin_amdgcn_sched_barrier(0);
    const float z3 = zbatch(a3);

    // shared softmax7: lane-group q handles batch wave*4+q
    float z = (q == 1) ? z1 : z0;
    z = (q == 2) ? z2 : z;
    z = (q == 3) ? z3 : z;
    float e = (col < 7) ? __builtin_amdgcn_exp2f(z) : 0.0f;
    float s = e;
    s += ROR(s, 1); s += ROR(s, 2); s += ROR(s, 4); s += ROR(s, 8);
    if (col < 7) __builtin_nontemporal_store(e * __builtin_amdgcn_rcpf(s), op);
}

extern "C" void kernel_launch(void* const* d_in, const int* in_sizes, int n_in,
                              void* d_out, int out_size, void* d_ws, size_t ws_size,
                              hipStream_t stream) {
    (void)in_sizes; (void)n_in; (void)out_size; (void)ws_size;
    const float* smp = (const float*)d_in[0];
    float* ws = (float*)d_ws;
    hop_prep<<<1, 256, 0, stream>>>(
        (const float*)d_in[1],  (const float*)d_in[2],   // ln_q_g, ln_q_b
        (const float*)d_in[3],                           // ln_k_g
        (const float*)d_in[5],  (const float*)d_in[6],   // ln_v_g, ln_v_b
        (const float*)d_in[7],  (const float*)d_in[8],   // Wq, bq
        (const float*)d_in[9],                           // Wk
        (const float*)d_in[11], (const float*)d_in[12],  // Wv, bv
        (const float*)d_in[13], (const float*)d_in[14],  // Wo, bo
        (const float*)d_in[15], (const float*)d_in[16],  // Wm, bm
        (const float*)d_in[17], (const float*)d_in[18],  // Wb, bb
        ws);
    hop_main<<<NBATCH * 16 / 256, 256, 0, stream>>>(smp, ws, (float*)d_out);
}